// Round 1
// baseline (84.820 us; speedup 1.0000x reference)
//
#include <hip/hip_runtime.h>

// ABELSpline: B=1024, D=128, DENSITY=259, ODIM=64, IDIM=512
// out[b,o] = direct[b,o] + sum_n c_n*(exp(z[b,o*8+n]) - exp(z[b,o*8+4+n])),
//   c_n = (n+1)^-2   (== exp bias -2*log(n+1))
// direct[b,o] = sum_{d,k} w[b,d,k] * dtab[d*259 + p[b,d] + k, o]
// z[b,j]      = sum_{d,k} w[b,d,k] * itab[d*259 + p[b,d] + k, j]
// p = floor(256*x), w = cubic B-spline basis of frac(256*x).
// Note: p+k <= 258 < 259, so the reference's mod DENSITY never wraps.

constexpr int BATCH = 1024;
constexpr int DIN = 128;
constexpr int DENSITY = 259;
constexpr int ODIM = 64;
constexpr int IDIM = 512;

__device__ __forceinline__ void fma4(float4& a, float s, const float4 v) {
    a.x = fmaf(s, v.x, a.x);
    a.y = fmaf(s, v.y, a.y);
    a.z = fmaf(s, v.z, a.z);
    a.w = fmaf(s, v.w, a.w);
}

__global__ __launch_bounds__(128) void abel_spline_kernel(
    const float* __restrict__ x,
    const float* __restrict__ dtab,
    const float* __restrict__ itab,
    float* __restrict__ out)
{
    __shared__ float4 s_w[DIN];     // 4 spline weights per input dim
    __shared__ int    s_base[DIN];  // d*259 + floor(256*x_d)
    __shared__ float  s_z[IDIM];    // indirect accumulators
    __shared__ float  s_dir[ODIM];  // direct accumulators

    const int b   = blockIdx.x;
    const int tid = threadIdx.x;

    // ---- phase 1: per-dim spline weights + base row index (128 threads == 128 dims)
    {
        float xv = x[b * DIN + tid];
        float t  = xv * 256.0f;          // scale = DENSITY-3 = 256 (exact pow2)
        float fl = floorf(t);            // 0..255
        float f  = t - fl;               // frac in [0,1)
        float f2 = f * f;
        float f3 = f2 * f;
        float om = 1.0f - f;
        float w0 = om * om * om * (1.0f / 6.0f);                       // knot p+0
        float w1 = (3.0f * f3 - 6.0f * f2 + 4.0f) * (1.0f / 6.0f);     // knot p+1
        float w2 = (-3.0f * f3 + 3.0f * f2 + 3.0f * f + 1.0f) * (1.0f / 6.0f); // p+2
        float w3 = f3 * (1.0f / 6.0f);                                 // knot p+3
        s_w[tid]    = make_float4(w0, w1, w2, w3);
        s_base[tid] = tid * DENSITY + (int)fl;
    }
    __syncthreads();

    const float4* __restrict__ it4 = reinterpret_cast<const float4*>(itab); // row stride 128 f4
    const float4* __restrict__ dt4 = reinterpret_cast<const float4*>(dtab); // row stride 16 f4

    float4 aI = make_float4(0.f, 0.f, 0.f, 0.f);  // indirect cols 4*tid..4*tid+3
    float4 aD = make_float4(0.f, 0.f, 0.f, 0.f);  // direct cols 4*tid..4*tid+3 (tid<16)
    const bool doD = (tid < 16);

    // ---- phase 2: weighted gather-reduce over 128 dims x 4 knots
    for (int d = 0; d < DIN; ++d) {
        const int    base = s_base[d];
        const float4 w    = s_w[d];

        const float4* r = it4 + (size_t)base * (IDIM / 4) + tid;
        float4 v0 = r[0 * (IDIM / 4)];
        float4 v1 = r[1 * (IDIM / 4)];
        float4 v2 = r[2 * (IDIM / 4)];
        float4 v3 = r[3 * (IDIM / 4)];
        fma4(aI, w.x, v0);
        fma4(aI, w.y, v1);
        fma4(aI, w.z, v2);
        fma4(aI, w.w, v3);

        if (doD) {
            const float4* rd = dt4 + (size_t)base * (ODIM / 4) + tid;
            float4 u0 = rd[0 * (ODIM / 4)];
            float4 u1 = rd[1 * (ODIM / 4)];
            float4 u2 = rd[2 * (ODIM / 4)];
            float4 u3 = rd[3 * (ODIM / 4)];
            fma4(aD, w.x, u0);
            fma4(aD, w.y, u1);
            fma4(aD, w.z, u2);
            fma4(aD, w.w, u3);
        }
    }

    reinterpret_cast<float4*>(s_z)[tid] = aI;
    if (doD) reinterpret_cast<float4*>(s_dir)[tid] = aD;
    __syncthreads();

    // ---- phase 3: anti-symmetric exponential combine (64 outputs)
    if (tid < ODIM) {
        const float* zp = s_z + tid * 8;
        float pos = __expf(zp[0]) + 0.25f * __expf(zp[1])
                  + (1.0f / 9.0f) * __expf(zp[2]) + 0.0625f * __expf(zp[3]);
        float neg = __expf(zp[4]) + 0.25f * __expf(zp[5])
                  + (1.0f / 9.0f) * __expf(zp[6]) + 0.0625f * __expf(zp[7]);
        out[b * ODIM + tid] = s_dir[tid] + pos - neg;
    }
}

extern "C" void kernel_launch(void* const* d_in, const int* in_sizes, int n_in,
                              void* d_out, int out_size, void* d_ws, size_t ws_size,
                              hipStream_t stream) {
    const float* x    = (const float*)d_in[0];
    const float* dtab = (const float*)d_in[1];
    const float* itab = (const float*)d_in[2];
    float* out = (float*)d_out;
    hipLaunchKernelGGL(abel_spline_kernel, dim3(BATCH), dim3(DIN), 0, stream,
                       x, dtab, itab, out);
}